// Round 5
// baseline (36.968 us; speedup 1.0000x reference)
//
#include <hip/hip_runtime.h>
#include <cstdint>

#define IN_F 128
#define OUT_F 128
#define NPB 8       // nodes per block
#define WAVES 16
#define THREADS 1024
#define STRIP 64    // j-columns per wave (N / WAVES)
#define NEG_BIG -1e30f

typedef _Float16 h2 __attribute__((ext_vector_type(2)));
typedef float    f2 __attribute__((ext_vector_type(2)));

union H2U { unsigned u; h2 v; };

// ---- pre-pass: h f32 -> packed f16 pairs in workspace ----
__global__ void cvt_kernel(const float* __restrict__ h,
                           unsigned* __restrict__ h16, int n2)
{
    const int i = blockIdx.x * blockDim.x + threadIdx.x;
    if (i < n2) {
        const float2 v = ((const float2*)h)[i];
        H2U p;
        p.v.x = (_Float16)v.x;
        p.v.y = (_Float16)v.y;
        h16[i] = p.u;
    }
}

__global__ __launch_bounds__(THREADS, 4) void sage_kernel(
    const float* __restrict__ h, const unsigned* __restrict__ h16,
    const int* __restrict__ adj,
    const float* __restrict__ Ws, const float* __restrict__ bs,
    const float* __restrict__ Wn, const float* __restrict__ bn,
    const float* __restrict__ gamma, const float* __restrict__ beta,
    float* __restrict__ out, int N)
{
    __shared__ unsigned part[WAVES][NPB][64];  // packed f16 partials, 32 KB
    __shared__ unsigned anyw_s[WAVES];
    __shared__ float h_self[NPB][IN_F];        // 4 KB
    __shared__ float agg_s[NPB][IN_F];         // 4 KB
    __shared__ float out_s[NPB][OUT_F];        // 4 KB

    const int t    = threadIdx.x;
    const int w    = t >> 6;
    const int lane = t & 63;

    const int base = blockIdx.x * NPB;
    const int b    = base / N;
    const int i0   = base - b * N;

    const float*    hb    = h   + (size_t)b * N * IN_F;
    const unsigned* h16b  = h16 + (size_t)b * N * (IN_F / 2);
    const int*      adjb  = adj + (size_t)b * N * N;
    const int jbase       = w * STRIP;

    // ---- one 64-bit mask per node over this wave's 64-column strip ----
    unsigned long long m[NPB];
    unsigned anybits = 0;
    #pragma unroll
    for (int n = 0; n < NPB; ++n) {
        const int i_n = i0 + n;
        const int j   = jbase + lane;
        m[n] = __ballot(adjb[(size_t)i_n * N + j] != 0 && j != i_n);
        anybits |= (m[n] != 0ull ? 1u : 0u) << n;
    }

    // ---- dense masked-max scan in packed f16: pk_min(cap) + pk_max ----
    const unsigned NEGINF2 = 0xFC00FC00u;  // (-inf,-inf)
    const unsigned POSINF2 = 0x7C007C00u;  // (+inf,+inf)

    H2U a[NPB];
    #pragma unroll
    for (int n = 0; n < NPB; ++n) a[n].u = NEGINF2;

    const unsigned* hrow = h16b + (size_t)jbase * (IN_F / 2) + lane;

    #pragma unroll 8
    for (int k = 0; k < STRIP; ++k) {
        H2U v; v.u = hrow[(size_t)k * (IN_F / 2)];
        #pragma unroll
        for (int n = 0; n < NPB; ++n) {
            H2U cap; cap.u = ((m[n] >> k) & 1ull) ? POSINF2 : NEGINF2;  // s_cselect
            a[n].v = __builtin_elementwise_max(a[n].v,
                         __builtin_elementwise_min(v.v, cap.v));  // v_pk_min/max_f16
        }
    }

    #pragma unroll
    for (int n = 0; n < NPB; ++n) part[w][n][lane] = a[n].u;
    if (lane == 0) anyw_s[w] = anybits;
    __syncthreads();

    // ---- combine partials (waves 0-7) / stage h_self (waves 8-15) ----
    if (w < NPB) {
        H2U r; r.u = part[0][w][lane];
        #pragma unroll
        for (int wp = 1; wp < WAVES; ++wp) {
            H2U p; p.u = part[wp][w][lane];
            r.v = __builtin_elementwise_max(r.v, p.v);
        }
        unsigned anyall = 0;
        #pragma unroll
        for (int wp = 0; wp < WAVES; ++wp) anyall |= anyw_s[wp];
        float rx = (float)r.v.x;
        float ry = (float)r.v.y;
        const float2 hs = *(const float2*)&hb[(size_t)(i0 + w) * IN_F + 2 * lane];
        if (!((anyall >> w) & 1u)) { rx = hs.x; ry = hs.y; }
        *(float2*)&agg_s[w][2 * lane] = make_float2(rx, ry);
    } else {
        const int n2 = w - NPB;
        const float2 hs = *(const float2*)&hb[(size_t)(i0 + n2) * IN_F + 2 * lane];
        *(float2*)&h_self[n2][2 * lane] = hs;
    }
    __syncthreads();

    // ---- GEMMs + bias: thread -> (node = t>>7, o = t&127) ----
    const int o    = t & (OUT_F - 1);
    const int node = t >> 7;
    float acc = bs[o] + bn[o];
    #pragma unroll 8
    for (int f = 0; f < IN_F; ++f) {
        acc = fmaf(h_self[node][f], Ws[f * OUT_F + o], acc);
        acc = fmaf(agg_s[node][f],  Wn[f * OUT_F + o], acc);
    }
    out_s[node][o] = acc;
    __syncthreads();

    // ---- LayerNorm + ReLU (waves 0-7, node w) ----
    if (w < NPB) {
        const float x0 = out_s[w][lane];
        const float x1 = out_s[w][lane + 64];
        float s  = x0 + x1;
        float s2 = x0 * x0 + x1 * x1;
        #pragma unroll
        for (int d = 32; d >= 1; d >>= 1) {
            s  += __shfl_xor(s, d, 64);
            s2 += __shfl_xor(s2, d, 64);
        }
        const float mu  = s * (1.0f / OUT_F);
        const float var = s2 * (1.0f / OUT_F) - mu * mu;
        const float rs  = rsqrtf(var + 1e-5f);

        float* orow = out + (size_t)(base + w) * OUT_F;
        const float r0 = (x0 - mu) * rs * gamma[lane]      + beta[lane];
        const float r1 = (x1 - mu) * rs * gamma[lane + 64] + beta[lane + 64];
        orow[lane]      = fmaxf(r0, 0.0f);
        orow[lane + 64] = fmaxf(r1, 0.0f);
    }
}

extern "C" void kernel_launch(void* const* d_in, const int* in_sizes, int n_in,
                              void* d_out, int out_size, void* d_ws, size_t ws_size,
                              hipStream_t stream) {
    const float* h     = (const float*)d_in[0];
    const int*   adj   = (const int*)d_in[1];
    const float* Ws    = (const float*)d_in[2];
    const float* bs    = (const float*)d_in[3];
    const float* Wn    = (const float*)d_in[4];
    const float* bn    = (const float*)d_in[5];
    const float* gamma = (const float*)d_in[6];
    const float* beta  = (const float*)d_in[7];
    float* out = (float*)d_out;
    unsigned* h16 = (unsigned*)d_ws;

    const long long bn_nodes = in_sizes[0] / IN_F;          // B*N
    const int N = (int)((long long)in_sizes[1] / bn_nodes); // adj is B*N*N
    const int grid = (int)(bn_nodes / NPB);

    const int n2 = in_sizes[0] / 2;                         // half2 count
    hipLaunchKernelGGL(cvt_kernel, dim3((n2 + 255) / 256), dim3(256), 0, stream,
                       h, h16, n2);
    hipLaunchKernelGGL(sage_kernel, dim3(grid), dim3(THREADS), 0, stream,
                       h, h16, adj, Ws, bs, Wn, bn, gamma, beta, out, N);
}

// Round 6
// 32.159 us; speedup vs baseline: 1.1496x; 1.1496x over previous
//
#include <hip/hip_runtime.h>
#include <cstdint>

#define IN_F 128
#define OUT_F 128
#define NPB 8       // nodes per block
#define WAVES 16
#define THREADS 1024
#define STRIP 64    // j-columns per wave (N / WAVES)
#define NEG_BIG -1e30f

typedef _Float16 h2v __attribute__((ext_vector_type(2)));
union H2U { unsigned u; h2v v; };

// ---- pre-pass: h f32 -> packed f16 pairs in workspace ----
__global__ void cvt_kernel(const float* __restrict__ h,
                           unsigned* __restrict__ h16, int n2)
{
    const int i = blockIdx.x * blockDim.x + threadIdx.x;
    if (i < n2) {
        const float2 v = ((const float2*)h)[i];
        H2U p; p.v.x = (_Float16)v.x; p.v.y = (_Float16)v.y;
        h16[i] = p.u;
    }
}

__global__ __launch_bounds__(THREADS, 2) void sage_kernel(
    const float* __restrict__ h, const unsigned* __restrict__ h16,
    const int* __restrict__ adj,
    const float* __restrict__ Ws, const float* __restrict__ bs,
    const float* __restrict__ Wn, const float* __restrict__ bn,
    const float* __restrict__ gamma, const float* __restrict__ beta,
    float* __restrict__ out, int N)
{
    // 32 KB buffer, time-shared: scan partials -> GEMM partials
    __shared__ __align__(16) char spraw[WAVES * NPB * 64 * 4];
    auto scanp = (unsigned (*)[NPB][64])spraw;      // [WAVES][NPB][64]
    auto gemmp = (float (*)[NPB][OUT_F])spraw;      // [NPB][NPB][OUT_F]

    __shared__ unsigned anyw_s[WAVES];
    __shared__ float h_self[NPB][IN_F];             // 4 KB
    __shared__ float agg_s[NPB][IN_F];              // 4 KB
    __shared__ float out_s[NPB][OUT_F];             // 4 KB

    const int t    = threadIdx.x;
    const int w    = t >> 6;
    const int lane = t & 63;

    const int base = blockIdx.x * NPB;
    const int b    = base / N;
    const int i0   = base - b * N;

    const float*    hb   = h   + (size_t)b * N * IN_F;
    const unsigned* h16b = h16 + (size_t)b * N * (IN_F / 2);
    const int*      adjb = adj + (size_t)b * N * N;
    const int jbase      = w * STRIP;

    // ---- one 64-bit mask per node over this wave's 64-column strip ----
    unsigned long long m[NPB];
    unsigned anybits = 0;
    #pragma unroll
    for (int n = 0; n < NPB; ++n) {
        const int i_n = i0 + n;
        const int j   = jbase + lane;
        m[n] = __ballot(adjb[(size_t)i_n * N + j] != 0 && j != i_n);
        anybits |= (m[n] != 0ull ? 1u : 0u) << n;
    }

    // ---- dense masked-max scan in packed f16: pk_min(cap) + pk_max ----
    const unsigned NEGINF2 = 0xFC00FC00u;  // (-inf,-inf)
    const unsigned POSINF2 = 0x7C007C00u;  // (+inf,+inf)

    H2U a[NPB];
    #pragma unroll
    for (int n = 0; n < NPB; ++n) a[n].u = NEGINF2;

    const unsigned* hrow = h16b + (size_t)jbase * (IN_F / 2) + lane;

    #pragma unroll 8
    for (int k = 0; k < STRIP; ++k) {
        H2U v; v.u = hrow[(size_t)k * (IN_F / 2)];
        #pragma unroll
        for (int n = 0; n < NPB; ++n) {
            H2U cap; cap.u = ((m[n] >> k) & 1ull) ? POSINF2 : NEGINF2;  // s_cselect
            a[n].v = __builtin_elementwise_max(a[n].v,
                         __builtin_elementwise_min(v.v, cap.v));        // v_pk_min/max_f16
        }
    }

    #pragma unroll
    for (int n = 0; n < NPB; ++n) scanp[w][n][lane] = a[n].u;
    if (lane == 0) anyw_s[w] = anybits;
    __syncthreads();

    // ---- combine partials (waves 0-7) / stage h_self (waves 8-15) ----
    if (w < NPB) {
        H2U r; r.u = scanp[0][w][lane];
        #pragma unroll
        for (int wp = 1; wp < WAVES; ++wp) {
            H2U p; p.u = scanp[wp][w][lane];
            r.v = __builtin_elementwise_max(r.v, p.v);
        }
        unsigned anyall = 0;
        #pragma unroll
        for (int wp = 0; wp < WAVES; ++wp) anyall |= anyw_s[wp];
        float rx = (float)r.v.x;
        float ry = (float)r.v.y;
        const float2 hs = *(const float2*)&hb[(size_t)(i0 + w) * IN_F + 2 * lane];
        if (!((anyall >> w) & 1u)) { rx = hs.x; ry = hs.y; }
        *(float2*)&agg_s[w][2 * lane] = make_float2(rx, ry);
    } else {
        const int n2 = w - NPB;
        const float2 hs = *(const float2*)&hb[(size_t)(i0 + n2) * IN_F + 2 * lane];
        *(float2*)&h_self[n2][2 * lane] = hs;
    }
    __syncthreads();   // scanp fully consumed; gemmp may now overwrite it

    // ---- GEMMs: thread (o = t&127, fchunk = t>>7) handles ALL 8 nodes ----
    // weight column read ONCE per (f,o) in the block (no 8x redundancy)
    {
        const int o  = t & (OUT_F - 1);
        const int fc = t >> 7;               // wave-uniform (w>>1)
        float acc[NPB];
        #pragma unroll
        for (int n = 0; n < NPB; ++n) acc[n] = 0.0f;

        const int f0 = fc * (IN_F / NPB);    // 16 f's per chunk
        #pragma unroll
        for (int ff = 0; ff < IN_F / NPB; ++ff) {
            const int f = f0 + ff;
            const float ws = Ws[f * OUT_F + o];
            const float wn = Wn[f * OUT_F + o];
            #pragma unroll
            for (int n = 0; n < NPB; ++n) {
                acc[n] = fmaf(h_self[n][f], ws, acc[n]);  // uniform LDS broadcast
                acc[n] = fmaf(agg_s[n][f],  wn, acc[n]);
            }
        }
        #pragma unroll
        for (int n = 0; n < NPB; ++n) gemmp[fc][n][o] = acc[n];
    }
    __syncthreads();

    // ---- reduce partials over fchunks + bias ----
    {
        const int o    = t & (OUT_F - 1);
        const int node = t >> 7;
        float acc = bs[o] + bn[o];
        #pragma unroll
        for (int fc = 0; fc < NPB; ++fc) acc += gemmp[fc][node][o];
        out_s[node][o] = acc;
    }
    __syncthreads();

    // ---- LayerNorm + ReLU (waves 0-7, node w) ----
    if (w < NPB) {
        const float x0 = out_s[w][lane];
        const float x1 = out_s[w][lane + 64];
        float s  = x0 + x1;
        float s2 = x0 * x0 + x1 * x1;
        #pragma unroll
        for (int d = 32; d >= 1; d >>= 1) {
            s  += __shfl_xor(s, d, 64);
            s2 += __shfl_xor(s2, d, 64);
        }
        const float mu  = s * (1.0f / OUT_F);
        const float var = s2 * (1.0f / OUT_F) - mu * mu;
        const float rs  = rsqrtf(var + 1e-5f);

        float* orow = out + (size_t)(base + w) * OUT_F;
        const float r0 = (x0 - mu) * rs * gamma[lane]      + beta[lane];
        const float r1 = (x1 - mu) * rs * gamma[lane + 64] + beta[lane + 64];
        orow[lane]      = fmaxf(r0, 0.0f);
        orow[lane + 64] = fmaxf(r1, 0.0f);
    }
}

extern "C" void kernel_launch(void* const* d_in, const int* in_sizes, int n_in,
                              void* d_out, int out_size, void* d_ws, size_t ws_size,
                              hipStream_t stream) {
    const float* h     = (const float*)d_in[0];
    const int*   adj   = (const int*)d_in[1];
    const float* Ws    = (const float*)d_in[2];
    const float* bs    = (const float*)d_in[3];
    const float* Wn    = (const float*)d_in[4];
    const float* bn    = (const float*)d_in[5];
    const float* gamma = (const float*)d_in[6];
    const float* beta  = (const float*)d_in[7];
    float* out = (float*)d_out;
    unsigned* h16 = (unsigned*)d_ws;

    const long long bn_nodes = in_sizes[0] / IN_F;          // B*N
    const int N = (int)((long long)in_sizes[1] / bn_nodes); // adj is B*N*N
    const int grid = (int)(bn_nodes / NPB);

    const int n2 = in_sizes[0] / 2;                         // half2 count
    hipLaunchKernelGGL(cvt_kernel, dim3((n2 + 255) / 256), dim3(256), 0, stream,
                       h, h16, n2);
    hipLaunchKernelGGL(sage_kernel, dim3(grid), dim3(THREADS), 0, stream,
                       h, h16, adj, Ws, bs, Wn, bn, gamma, beta, out, N);
}